// Round 5
// baseline (889.662 us; speedup 1.0000x reference)
//
#include <hip/hip_runtime.h>
#include <hip/hip_bf16.h>
#include <math.h>

#define V 65536
#define G 2048
#define NPG 32
#define DEG 4
#define NE (V*DEG)
#define H 200
#define NODE_IN 74
#define EDGE_IN 12
#define NL 5

#define KP 224      // GEMM K padded (7 x 32)
#define NP 208      // feature dim padded (13 x 16)
#define AGS 225     // agg LDS row stride in u32 (225%32=1 -> <=2-way banks on b128 reads)
#define EK 32       // edge-mfma K
#define HS 200      // h_s row stride (floats)
#define NFS 200     // Anf row stride (u16): [hi 96 | lo 96 | pad 8]

typedef __attribute__((ext_vector_type(8))) short short8;
typedef __attribute__((ext_vector_type(4))) float floatx4;

__device__ __forceinline__ float sigmoidf_(float x) { return 1.f / (1.f + __expf(-x)); }

__device__ __forceinline__ unsigned f2bf_bits(float f) {
    unsigned u = __float_as_uint(f);
    return (u + 0x7fffu + ((u >> 16) & 1u)) >> 16;  // RNE
}
__device__ __forceinline__ float bf2f(unsigned bits) { return __uint_as_float(bits << 16); }
__device__ __forceinline__ unsigned lo_bits(float f, unsigned hb) {
    return f2bf_bits(f - bf2f(hb));
}

// ---------------- prep: gnn_W -> transposed hi/lo bf16 planes [NL][NP][KP] ----------------
__global__ __launch_bounds__(256) void k_prep_w(const float* __restrict__ gnnW,
                                                unsigned short* __restrict__ WtHi,
                                                unsigned short* __restrict__ WtLo) {
    int idx = blockIdx.x * 256 + threadIdx.x;
    if (idx >= NL * NP * KP) return;
    int l = idx / (NP * KP);
    int rem = idx - l * NP * KP;
    int n = rem / KP;
    int k = rem - n * KP;
    float w = (n < H && k < H) ? gnnW[l * H * H + k * H + n] : 0.f;
    unsigned hb = f2bf_bits(w);
    WtHi[idx] = (unsigned short)hb;
    WtLo[idx] = (unsigned short)lo_bits(w, hb);
}

// ---------------- prep: edge_W/edge_b -> B planes [NP][64] ----------------
__global__ __launch_bounds__(256) void k_prep_ew(const float* __restrict__ eW,
                                                 const float* __restrict__ eb,
                                                 unsigned short* __restrict__ eWp) {
    int t = threadIdx.x;
    if (t >= NP) return;
    unsigned short row[64];
    for (int i = 0; i < 64; i++) row[i] = 0;
    if (t < H) {
        for (int k = 0; k < EDGE_IN; k++) {
            float w = eW[k * H + t];
            unsigned hb = f2bf_bits(w);
            row[k] = (unsigned short)hb;
            row[12 + k] = (unsigned short)hb;
            row[32 + k] = (unsigned short)lo_bits(w, hb);
        }
        float e = eb[t];
        unsigned ebh = f2bf_bits(e);
        row[24] = (unsigned short)ebh;
        row[25] = (unsigned short)lo_bits(e, ebh);
    }
    for (int i = 0; i < 64; i++) eWp[t * 64 + i] = row[i];
}

// ---------------- prep: ef -> edge A-plane [NE][EK]: [hi12 | lo12 | 1,1 | 0...] ----------------
__global__ __launch_bounds__(256) void k_prep_ef(const float* __restrict__ ef,
                                                 unsigned short* __restrict__ Aedge) {
    __shared__ float efs[256 * EDGE_IN];
    const int tid = threadIdx.x, blk = blockIdx.x;
    const float4* gs = (const float4*)(ef + (size_t)blk * 256 * EDGE_IN);
    float4* ds = (float4*)efs;
    for (int p = tid; p < 256 * EDGE_IN / 4; p += 256) ds[p] = gs[p];
    __syncthreads();
    unsigned hb[EDGE_IN], lb[EDGE_IN];
    for (int k = 0; k < EDGE_IN; k++) {
        float v = efs[tid * EDGE_IN + k];
        hb[k] = f2bf_bits(v);
        lb[k] = lo_bits(v, hb[k]);
    }
    unsigned w[16];
    for (int i = 0; i < 6; i++) w[i] = hb[2 * i] | (hb[2 * i + 1] << 16);
    for (int i = 0; i < 6; i++) w[6 + i] = lb[2 * i] | (lb[2 * i + 1] << 16);
    w[12] = 0x3F803F80u;  // k24,k25 = 1.0 (bias rows)
    w[13] = 0u; w[14] = 0u; w[15] = 0u;
    uint4* dst = (uint4*)(Aedge + ((size_t)blk * 256 + tid) * EK);
    dst[0] = make_uint4(w[0], w[1], w[2], w[3]);
    dst[1] = make_uint4(w[4], w[5], w[6], w[7]);
    dst[2] = make_uint4(w[8], w[9], w[10], w[11]);
    dst[3] = make_uint4(w[12], w[13], w[14], w[15]);
}

// ---------------- prep: node_feat -> A planes [V][NFS] ----------------
__global__ __launch_bounds__(256) void k_prep_nf(const float* __restrict__ nf,
                                                 unsigned int* __restrict__ Anf) {
    __shared__ float nf_s[64 * NODE_IN];
    const int tid = threadIdx.x, blk = blockIdx.x;
    const float4* gs = (const float4*)(nf + (size_t)blk * 64 * NODE_IN);
    float4* ds = (float4*)nf_s;
    for (int p = tid; p < 64 * NODE_IN / 4; p += 256) ds[p] = gs[p];
    __syncthreads();
    for (int p = tid; p < 64 * 100; p += 256) {
        int row = p / 100, c = p - row * 100;
        unsigned v0 = 0, v1 = 0;
        if (c < 48) {
            int k0 = 2 * c;
            if (k0 < NODE_IN) v0 = f2bf_bits(nf_s[row * NODE_IN + k0]);
            else if (k0 == 74 || k0 == 75) v0 = 0x3F80u;
            int k1 = k0 + 1;
            if (k1 < NODE_IN) v1 = f2bf_bits(nf_s[row * NODE_IN + k1]);
            else if (k1 == 74 || k1 == 75) v1 = 0x3F80u;
        } else if (c < 96) {
            int k0 = 2 * (c - 48);
            if (k0 < NODE_IN) { float x = nf_s[row * NODE_IN + k0]; v0 = lo_bits(x, f2bf_bits(x)); }
            int k1 = k0 + 1;
            if (k1 < NODE_IN) { float x = nf_s[row * NODE_IN + k1]; v1 = lo_bits(x, f2bf_bits(x)); }
        }
        Anf[((size_t)blk * 64 + row) * 100 + c] = v0 | (v1 << 16);
    }
}

// ---------------- prep: node_W/node_b -> B planes [NP][192] ----------------
__global__ __launch_bounds__(256) void k_prep_nw(const float* __restrict__ nW,
                                                 const float* __restrict__ nb,
                                                 unsigned int* __restrict__ BnW) {
    int idx = blockIdx.x * 256 + threadIdx.x;
    if (idx >= NP * 96) return;
    int jj = idx / 96, c = idx - jj * 96;
    unsigned v0 = 0, v1 = 0;
    if (jj < H) {
        if (c < 48) {
            int k0 = 2 * c, k1 = k0 + 1;
            if (k0 < NODE_IN) v0 = f2bf_bits(nW[k0 * H + jj]);
            else if (k0 == 74) v0 = f2bf_bits(nb[jj]);
            else if (k0 == 75) { float b = nb[jj]; v0 = lo_bits(b, f2bf_bits(b)); }
            if (k1 < NODE_IN) v1 = f2bf_bits(nW[k1 * H + jj]);
            else if (k1 == 74) v1 = f2bf_bits(nb[jj]);
            else if (k1 == 75) { float b = nb[jj]; v1 = lo_bits(b, f2bf_bits(b)); }
        } else {
            int k0 = 2 * (c - 48), k1 = k0 + 1;
            if (k0 < NODE_IN) { float x = nW[k0 * H + jj]; v0 = lo_bits(x, f2bf_bits(x)); }
            if (k1 < NODE_IN) { float x = nW[k1 * H + jj]; v1 = lo_bits(x, f2bf_bits(x)); }
        }
    }
    BnW[idx] = v0 | (v1 << 16);
}

// ---------------- MEGA: embed + 5 GNN layers + gf, one block per graph, 3 blocks/CU ----------------
__global__ __launch_bounds__(256, 3) void k_mega(const unsigned short* __restrict__ Anf,
                                                 const unsigned short* __restrict__ BnW,
                                                 const unsigned short* __restrict__ Aedge,
                                                 const unsigned short* __restrict__ eWp,
                                                 const int* __restrict__ src,
                                                 const unsigned short* __restrict__ WtHi,
                                                 const unsigned short* __restrict__ WtLo,
                                                 const float* __restrict__ gnn_b,
                                                 float* __restrict__ h_out,
                                                 float* __restrict__ gf_out) {
    __shared__ alignas(16) float h_s[NPG * HS];           // 25600 B
    __shared__ alignas(16) unsigned int agg[NPG * AGS];   // 28800 B (also Anf staging)
    __shared__ unsigned char src_s[NPG * DEG];            // 128 B   -> total 54528 B: 3 blocks/CU
    const int g = blockIdx.x, tid = threadIdx.x;
    const int nbase = g * NPG, ebase = g * NPG * DEG;

    const int wave = tid >> 6, lane = tid & 63;
    const int l15 = lane & 15, quad = lane >> 4;
    const int ntcnt = (wave == 0) ? 4 : 3;

    // edge A-fragments straight into registers (persist across all layers)
    short8 af[8];
    {
        const unsigned short* abase = Aedge + (size_t)ebase * EK;
#pragma unroll
        for (int mt = 0; mt < 8; mt++)
            af[mt] = *(const short8*)&abase[(16 * mt + l15) * EK + quad * 8];
    }
    if (tid < NPG * DEG) src_s[tid] = (unsigned char)(src[ebase + tid] - nbase);
    {
        const uint4* n4 = (const uint4*)(Anf + (size_t)nbase * NFS);
        uint4* d4 = (uint4*)agg;
        for (int p = tid; p < NPG * NFS * 2 / 16; p += 256) d4[p] = n4[p];
    }
    __syncthreads();

    // ---- embed: h = nf @ nW + nb (split-3 bf16 MFMA) ----
    {
        const unsigned short* nf_s = (const unsigned short*)agg;
        for (int i = 0; i < ntcnt; i++) {
            int nt = wave + 4 * i, jj = nt * 16 + l15;
            floatx4 acc[2];
            acc[0] = (floatx4){0.f, 0.f, 0.f, 0.f};
            acc[1] = (floatx4){0.f, 0.f, 0.f, 0.f};
            for (int ks = 0; ks < 3; ks++) {
                short8 bh = *(const short8*)&BnW[(size_t)jj * 192 + ks * 32 + quad * 8];
                short8 bl = *(const short8*)&BnW[(size_t)jj * 192 + 96 + ks * 32 + quad * 8];
#pragma unroll
                for (int mt = 0; mt < 2; mt++) {
                    const unsigned short* arow = nf_s + (16 * mt + l15) * NFS;
                    short8 ah = *(const short8*)&arow[ks * 32 + quad * 8];
                    short8 al = *(const short8*)&arow[96 + ks * 32 + quad * 8];
                    acc[mt] = __builtin_amdgcn_mfma_f32_16x16x32_bf16(ah, bh, acc[mt], 0, 0, 0);
                    acc[mt] = __builtin_amdgcn_mfma_f32_16x16x32_bf16(al, bh, acc[mt], 0, 0, 0);
                    acc[mt] = __builtin_amdgcn_mfma_f32_16x16x32_bf16(ah, bl, acc[mt], 0, 0, 0);
                }
            }
            if (jj < H) {
#pragma unroll
                for (int mt = 0; mt < 2; mt++)
#pragma unroll
                    for (int r = 0; r < 4; r++)
                        h_s[(16 * mt + quad * 4 + r) * HS + jj] = acc[mt][r];
            }
        }
    }
    __syncthreads();
    // zero agg K-pad (u32 words 208..223 per row); data words 0..207 rewritten each layer
    for (int p = tid; p < NPG * 16; p += 256) {
        int row = p >> 4, wd = p & 15;
        agg[row * AGS + 208 + wd] = 0u;
    }

    for (int l = 0; l < NL; l++) {
        // ---- phase 1: edge eh via MFMA + lane-local 4-edge softmax -> agg planes (LDS) ----
        for (int i = 0; i < ntcnt; i++) {
            int nt = wave + 4 * i, jj = nt * 16 + l15;
            short8 b1 = *(const short8*)&eWp[(size_t)jj * 64 + quad * 8];
            short8 b2 = *(const short8*)&eWp[(size_t)jj * 64 + 32 + quad * 8];
            int jc = jj < H ? jj : H - 1;
#pragma unroll
            for (int mt = 0; mt < 8; mt++) {
                floatx4 z = (floatx4){0.f, 0.f, 0.f, 0.f};
                z = __builtin_amdgcn_mfma_f32_16x16x32_bf16(af[mt], b1, z, 0, 0, 0);
                z = __builtin_amdgcn_mfma_f32_16x16x32_bf16(af[mt], b2, z, 0, 0, 0);
                const int node = 4 * mt + quad;
                float m0 = z[0] + h_s[src_s[node * 4 + 0] * HS + jc];
                float m1 = z[1] + h_s[src_s[node * 4 + 1] * HS + jc];
                float m2 = z[2] + h_s[src_s[node * 4 + 2] * HS + jc];
                float m3 = z[3] + h_s[src_s[node * 4 + 3] * HS + jc];
                float mx = fmaxf(fmaxf(m0, m1), fmaxf(m2, m3));
                float e0 = __expf(m0 - mx), e1 = __expf(m1 - mx);
                float e2 = __expf(m2 - mx), e3 = __expf(m3 - mx);
                float den = e0 + e1 + e2 + e3;
                float num = fmaf(m0, e0, fmaf(m1, e1, fmaf(m2, e2, m3 * e3)));
                float a = __fdividef(num, den);
                if (jj >= H) a = 0.f;
                unsigned hbb = f2bf_bits(a);
                unsigned lbb = lo_bits(a, hbb);
                unsigned short* rowp = (unsigned short*)(agg + node * AGS);
                int c = jj >> 3, o = jj & 7;
                rowp[c * 16 + o] = (unsigned short)hbb;
                rowp[c * 16 + 8 + o] = (unsigned short)lbb;
            }
        }
        __syncthreads();

        // ---- phase 2: C[32][200] = agg @ W (split-3 MFMA), epilogue into h_s ----
        floatx4 acc2[2][4];
#pragma unroll
        for (int mt = 0; mt < 2; mt++)
#pragma unroll
            for (int i = 0; i < 4; i++) acc2[mt][i] = (floatx4){0.f, 0.f, 0.f, 0.f};

        const unsigned short* WH = WtHi + (size_t)l * NP * KP;
        const unsigned short* WL = WtLo + (size_t)l * NP * KP;
#pragma unroll 2
        for (int ks = 0; ks < KP / 32; ks++) {
            short8 ah[2], al[2];
#pragma unroll
            for (int mt = 0; mt < 2; mt++) {
                int off = (16 * mt + l15) * AGS + (4 * ks + quad) * 8;
                ah[mt] = *(const short8*)&agg[off];
                al[mt] = *(const short8*)&agg[off + 4];
            }
#pragma unroll 4
            for (int i = 0; i < ntcnt; i++) {
                int nt = wave + 4 * i;
                size_t boff = (size_t)(16 * nt + l15) * KP + ks * 32 + quad * 8;
                short8 vbh = *(const short8*)&WH[boff];
                short8 vbl = *(const short8*)&WL[boff];
#pragma unroll
                for (int mt = 0; mt < 2; mt++) {
                    acc2[mt][i] = __builtin_amdgcn_mfma_f32_16x16x32_bf16(ah[mt], vbh, acc2[mt][i], 0, 0, 0);
                    acc2[mt][i] = __builtin_amdgcn_mfma_f32_16x16x32_bf16(al[mt], vbh, acc2[mt][i], 0, 0, 0);
                    acc2[mt][i] = __builtin_amdgcn_mfma_f32_16x16x32_bf16(ah[mt], vbl, acc2[mt][i], 0, 0, 0);
                }
            }
        }
        for (int i = 0; i < ntcnt; i++) {
            int nt = wave + 4 * i, jj = nt * 16 + l15;
            if (jj < H) {
                float bj = gnn_b[l * H + jj];
#pragma unroll
                for (int mt = 0; mt < 2; mt++) {
#pragma unroll
                    for (int r = 0; r < 4; r++) {
                        float v = acc2[mt][i][r] + bj;
                        v = v > 0.f ? v : 0.f;
                        h_s[(16 * mt + quad * 4 + r) * HS + jj] += v;
                    }
                }
            }
        }
        __syncthreads();
    }

    // ---- write h + gf ----
    {
        float4* dst = (float4*)(h_out + (size_t)nbase * H);
        const float4* srcp = (const float4*)h_s;
        for (int p = tid; p < NPG * H / 4; p += 256) dst[p] = srcp[p];
    }
    if (tid < H) {
        float s = 0.f;
        for (int n = 0; n < NPG; n++) s += h_s[n * HS + tid];
        gf_out[g * H + tid] = s;
    }
}

// ---------------- readout attention ----------------
__global__ __launch_bounds__(256) void k_attn(const float* __restrict__ h,
                                              const float* __restrict__ gf,
                                              const float* __restrict__ lgW,
                                              const float* __restrict__ lgb,
                                              const float* __restrict__ prW,
                                              const float* __restrict__ prb,
                                              float* __restrict__ ctx_out) {
    __shared__ float h_s[NPG][H];
    __shared__ float gf_s[H];
    __shared__ float zp[256];
    __shared__ float z_s[NPG];
    __shared__ float a_s[NPG];
    __shared__ float wh_s[H];
    __shared__ float wsum[4];
    const int g = blockIdx.x, tid = threadIdx.x;
    const int wave = tid >> 6, lane = tid & 63;

    for (int p = tid; p < NPG * H; p += 256) h_s[0][p] = h[g * NPG * H + p];
    if (tid < H) gf_s[tid] = gf[g * H + tid];
    __syncthreads();

    // c = dot(relu(gf), lgW[0:H]) via block reduction
    {
        float p = (tid < H) ? fmaxf(gf_s[tid], 0.f) * lgW[tid] : 0.f;
#pragma unroll
        for (int o = 32; o > 0; o >>= 1) p += __shfl_down(p, o);
        if (lane == 0) wsum[wave] = p;
    }

    // z partials: 8 threads per node
    {
        const int n = tid >> 3, l = tid & 7;
        float p = 0.f;
        for (int jj = l; jj < H; jj += 8) p = fmaf(h_s[n][jj], lgW[H + jj], p);
        zp[tid] = p;
    }
    __syncthreads();
    float c = (wsum[0] + wsum[1]) + (wsum[2] + wsum[3]);
    if (tid < NPG) {
        float z = c + lgb[0];
        for (int q = 0; q < 8; q++) z += zp[tid * 8 + q];
        z_s[tid] = z > 0.f ? z : 0.01f * z;
    }
    __syncthreads();
    float zmax = -1e30f;
    for (int n = 0; n < NPG; n++) zmax = fmaxf(zmax, z_s[n]);
    if (tid < NPG) a_s[tid] = __expf(z_s[tid] - zmax);
    __syncthreads();
    float den = 0.f;
    for (int n = 0; n < NPG; n++) den += a_s[n];

    if (tid < H) {
        float s = 0.f;
        for (int n = 0; n < NPG; n++) s = fmaf(a_s[n], h_s[n][tid], s);
        wh_s[tid] = s / den;
    }
    __syncthreads();

    if (tid < H) {
        float s0 = 0.f, s1 = 0.f, s2 = 0.f, s3 = 0.f;
        for (int i = 0; i < H; i += 4) {
            s0 = fmaf(wh_s[i + 0], prW[(i + 0) * H + tid], s0);
            s1 = fmaf(wh_s[i + 1], prW[(i + 1) * H + tid], s1);
            s2 = fmaf(wh_s[i + 2], prW[(i + 2) * H + tid], s2);
            s3 = fmaf(wh_s[i + 3], prW[(i + 3) * H + tid], s3);
        }
        float s = prb[tid] + ((s0 + s1) + (s2 + s3));
        ctx_out[g * H + tid] = s > 0.f ? s : __expf(s) - 1.f;
    }
}

// ---------------- GRU cell ----------------
#define GPB 8
#define GP 9
__global__ __launch_bounds__(256) void k_gru(const float* __restrict__ ctx,
                                             const float* __restrict__ gf,
                                             const float* __restrict__ Wih,
                                             const float* __restrict__ Whh,
                                             const float* __restrict__ bih,
                                             const float* __restrict__ bhh,
                                             float* __restrict__ gf_out) {
    __shared__ float ctx_s[GPB][H];
    __shared__ float gfs[GPB][H];
    __shared__ float gi_s[3 * H][GP];
    __shared__ float gh_s[3 * H][GP];
    const int gbase = blockIdx.x * GPB, tid = threadIdx.x;

    for (int p = tid; p < GPB * H; p += 256) {
        ctx_s[0][p] = ctx[gbase * H + p];
        gfs[0][p] = gf[gbase * H + p];
    }
    __syncthreads();

    for (int k = tid; k < 3 * H; k += 256) {
        float ai[GPB], ah[GPB];
        float bi = bih[k], bh = bhh[k];
#pragma unroll
        for (int q = 0; q < GPB; q++) { ai[q] = bi; ah[q] = bh; }
#pragma unroll 2
        for (int jj = 0; jj < H; jj++) {
            float wi = Wih[k * H + jj];
            float wh = Whh[k * H + jj];
#pragma unroll
            for (int q = 0; q < GPB; q++) {
                ai[q] = fmaf(ctx_s[q][jj], wi, ai[q]);
                ah[q] = fmaf(gfs[q][jj], wh, ah[q]);
            }
        }
#pragma unroll
        for (int q = 0; q < GPB; q++) { gi_s[k][q] = ai[q]; gh_s[k][q] = ah[q]; }
    }
    __syncthreads();

    for (int p = tid; p < GPB * H; p += 256) {
        int q = p / H, jj = p - q * H;
        float r = sigmoidf_(gi_s[jj][q] + gh_s[jj][q]);
        float u = sigmoidf_(gi_s[H + jj][q] + gh_s[H + jj][q]);
        float nn = tanhf(gi_s[2 * H + jj][q] + r * gh_s[2 * H + jj][q]);
        gf_out[(gbase + q) * H + jj] = (1.f - u) * nn + u * gfs[q][jj];
    }
}

extern "C" void kernel_launch(void* const* d_in, const int* in_sizes, int n_in,
                              void* d_out, int out_size, void* d_ws, size_t ws_size,
                              hipStream_t stream) {
    const float* node_feat = (const float*)d_in[0];
    const float* edge_feat = (const float*)d_in[1];
    const int* src = (const int*)d_in[2];
    const float* node_W = (const float*)d_in[5];
    const float* node_b = (const float*)d_in[6];
    const float* edge_W = (const float*)d_in[7];
    const float* edge_b = (const float*)d_in[8];
    const float* gnn_W = (const float*)d_in[9];
    const float* gnn_b = (const float*)d_in[10];
    const float* lg_W = (const float*)d_in[11];
    const float* lg_b = (const float*)d_in[12];
    const float* pr_W = (const float*)d_in[13];
    const float* pr_b = (const float*)d_in[14];
    const float* W_ih = (const float*)d_in[15];
    const float* W_hh = (const float*)d_in[16];
    const float* b_ih = (const float*)d_in[17];
    const float* b_hh = (const float*)d_in[18];
    float* out = (float*)d_out;

    char* ws = (char*)d_ws;
    size_t off = 0;
    auto alloc = [&](size_t bytes) { void* p = ws + off; off += (bytes + 4095) & ~(size_t)4095; return p; };
    float* h = (float*)alloc((size_t)V * H * 4);
    unsigned short* Anf = (unsigned short*)alloc((size_t)V * NFS * 2);
    unsigned short* Aedge = (unsigned short*)alloc((size_t)NE * EK * 2);
    unsigned short* WtHi = (unsigned short*)alloc((size_t)NL * NP * KP * 2);
    unsigned short* WtLo = (unsigned short*)alloc((size_t)NL * NP * KP * 2);
    unsigned short* BnW = (unsigned short*)alloc((size_t)NP * 192 * 2);
    unsigned short* eWp = (unsigned short*)alloc((size_t)NP * 64 * 2);
    float* gf_ws = (float*)alloc((size_t)G * H * 4);
    float* ctx_ws = (float*)alloc((size_t)G * H * 4);

    k_prep_w<<<(NL * NP * KP + 255) / 256, 256, 0, stream>>>(gnn_W, WtHi, WtLo);
    k_prep_ew<<<1, 256, 0, stream>>>(edge_W, edge_b, eWp);
    k_prep_ef<<<NE / 256, 256, 0, stream>>>(edge_feat, Aedge);
    k_prep_nf<<<V / 64, 256, 0, stream>>>(node_feat, (unsigned int*)Anf);
    k_prep_nw<<<(NP * 96 + 255) / 256, 256, 0, stream>>>(node_W, node_b, (unsigned int*)BnW);

    k_mega<<<G, 256, 0, stream>>>(Anf, BnW, Aedge, eWp, src, WtHi, WtLo, gnn_b, h, gf_ws);

    for (int t = 0; t < 2; t++) {
        k_attn<<<G, 256, 0, stream>>>(h, gf_ws, lg_W + (size_t)t * 2 * H, lg_b + t,
                                      pr_W + (size_t)t * H * H, pr_b + (size_t)t * H, ctx_ws);
        float* gout = (t == 1) ? out : gf_ws;
        k_gru<<<G / GPB, 256, 0, stream>>>(ctx_ws, gf_ws, W_ih + (size_t)t * 3 * H * H,
                                           W_hh + (size_t)t * 3 * H * H, b_ih + (size_t)t * 3 * H,
                                           b_hh + (size_t)t * 3 * H, gout);
    }
}

// Round 7
// 796.257 us; speedup vs baseline: 1.1173x; 1.1173x over previous
//
#include <hip/hip_runtime.h>
#include <hip/hip_bf16.h>
#include <math.h>

#define V 65536
#define G 2048
#define NPG 32
#define DEG 4
#define NE (V*DEG)
#define H 200
#define NODE_IN 74
#define EDGE_IN 12
#define NL 5

#define KP 224      // GEMM K padded (7 x 32)
#define NP 208      // feature dim padded (13 x 16)
#define AGS 209     // agg LDS row stride in u32: 26 chunks x 8 u32 + 1 (209%32=17 -> spread banks)
#define EK 32       // edge-mfma K
#define HS 200      // h_s row stride (floats)
#define NFS 200     // Anf row stride (u16): [hi 96 | lo 96 | pad 8]

typedef __attribute__((ext_vector_type(8))) short short8;
typedef __attribute__((ext_vector_type(4))) float floatx4;

__device__ __forceinline__ float sigmoidf_(float x) { return 1.f / (1.f + __expf(-x)); }

__device__ __forceinline__ unsigned f2bf_bits(float f) {
    unsigned u = __float_as_uint(f);
    return (u + 0x7fffu + ((u >> 16) & 1u)) >> 16;  // RNE
}
__device__ __forceinline__ float bf2f(unsigned bits) { return __uint_as_float(bits << 16); }
__device__ __forceinline__ unsigned lo_bits(float f, unsigned hb) {
    return f2bf_bits(f - bf2f(hb));
}

// ---------------- prep: gnn_W -> transposed hi/lo bf16 planes [NL][NP][KP] ----------------
__global__ __launch_bounds__(256) void k_prep_w(const float* __restrict__ gnnW,
                                                unsigned short* __restrict__ WtHi,
                                                unsigned short* __restrict__ WtLo) {
    int idx = blockIdx.x * 256 + threadIdx.x;
    if (idx >= NL * NP * KP) return;
    int l = idx / (NP * KP);
    int rem = idx - l * NP * KP;
    int n = rem / KP;
    int k = rem - n * KP;
    float w = (n < H && k < H) ? gnnW[l * H * H + k * H + n] : 0.f;
    unsigned hb = f2bf_bits(w);
    WtHi[idx] = (unsigned short)hb;
    WtLo[idx] = (unsigned short)lo_bits(w, hb);
}

// ---------------- prep: edge_W/edge_b -> B planes [NP][64] ----------------
__global__ __launch_bounds__(256) void k_prep_ew(const float* __restrict__ eW,
                                                 const float* __restrict__ eb,
                                                 unsigned short* __restrict__ eWp) {
    int t = threadIdx.x;
    if (t >= NP) return;
    unsigned short row[64];
    for (int i = 0; i < 64; i++) row[i] = 0;
    if (t < H) {
        for (int k = 0; k < EDGE_IN; k++) {
            float w = eW[k * H + t];
            unsigned hb = f2bf_bits(w);
            row[k] = (unsigned short)hb;
            row[12 + k] = (unsigned short)hb;
            row[32 + k] = (unsigned short)lo_bits(w, hb);
        }
        float e = eb[t];
        unsigned ebh = f2bf_bits(e);
        row[24] = (unsigned short)ebh;
        row[25] = (unsigned short)lo_bits(e, ebh);
    }
    for (int i = 0; i < 64; i++) eWp[t * 64 + i] = row[i];
}

// ---------------- prep: ef -> edge A-plane [NE][EK]: [hi12 | lo12 | 1,1 | 0...] ----------------
__global__ __launch_bounds__(256) void k_prep_ef(const float* __restrict__ ef,
                                                 unsigned short* __restrict__ Aedge) {
    __shared__ float efs[256 * EDGE_IN];
    const int tid = threadIdx.x, blk = blockIdx.x;
    const float4* gs = (const float4*)(ef + (size_t)blk * 256 * EDGE_IN);
    float4* ds = (float4*)efs;
    for (int p = tid; p < 256 * EDGE_IN / 4; p += 256) ds[p] = gs[p];
    __syncthreads();
    unsigned hb[EDGE_IN], lb[EDGE_IN];
    for (int k = 0; k < EDGE_IN; k++) {
        float v = efs[tid * EDGE_IN + k];
        hb[k] = f2bf_bits(v);
        lb[k] = lo_bits(v, hb[k]);
    }
    unsigned w[16];
    for (int i = 0; i < 6; i++) w[i] = hb[2 * i] | (hb[2 * i + 1] << 16);
    for (int i = 0; i < 6; i++) w[6 + i] = lb[2 * i] | (lb[2 * i + 1] << 16);
    w[12] = 0x3F803F80u;  // k24,k25 = 1.0 (bias rows)
    w[13] = 0u; w[14] = 0u; w[15] = 0u;
    uint4* dst = (uint4*)(Aedge + ((size_t)blk * 256 + tid) * EK);
    dst[0] = make_uint4(w[0], w[1], w[2], w[3]);
    dst[1] = make_uint4(w[4], w[5], w[6], w[7]);
    dst[2] = make_uint4(w[8], w[9], w[10], w[11]);
    dst[3] = make_uint4(w[12], w[13], w[14], w[15]);
}

// ---------------- prep: node_feat -> A planes [V][NFS] ----------------
__global__ __launch_bounds__(256) void k_prep_nf(const float* __restrict__ nf,
                                                 unsigned int* __restrict__ Anf) {
    __shared__ float nf_s[64 * NODE_IN];
    const int tid = threadIdx.x, blk = blockIdx.x;
    const float4* gs = (const float4*)(nf + (size_t)blk * 64 * NODE_IN);
    float4* ds = (float4*)nf_s;
    for (int p = tid; p < 64 * NODE_IN / 4; p += 256) ds[p] = gs[p];
    __syncthreads();
    for (int p = tid; p < 64 * 100; p += 256) {
        int row = p / 100, c = p - row * 100;
        unsigned v0 = 0, v1 = 0;
        if (c < 48) {
            int k0 = 2 * c;
            if (k0 < NODE_IN) v0 = f2bf_bits(nf_s[row * NODE_IN + k0]);
            else if (k0 == 74 || k0 == 75) v0 = 0x3F80u;
            int k1 = k0 + 1;
            if (k1 < NODE_IN) v1 = f2bf_bits(nf_s[row * NODE_IN + k1]);
            else if (k1 == 74 || k1 == 75) v1 = 0x3F80u;
        } else if (c < 96) {
            int k0 = 2 * (c - 48);
            if (k0 < NODE_IN) { float x = nf_s[row * NODE_IN + k0]; v0 = lo_bits(x, f2bf_bits(x)); }
            int k1 = k0 + 1;
            if (k1 < NODE_IN) { float x = nf_s[row * NODE_IN + k1]; v1 = lo_bits(x, f2bf_bits(x)); }
        }
        Anf[((size_t)blk * 64 + row) * 100 + c] = v0 | (v1 << 16);
    }
}

// ---------------- prep: node_W/node_b -> B planes [NP][192] ----------------
__global__ __launch_bounds__(256) void k_prep_nw(const float* __restrict__ nW,
                                                 const float* __restrict__ nb,
                                                 unsigned int* __restrict__ BnW) {
    int idx = blockIdx.x * 256 + threadIdx.x;
    if (idx >= NP * 96) return;
    int jj = idx / 96, c = idx - jj * 96;
    unsigned v0 = 0, v1 = 0;
    if (jj < H) {
        if (c < 48) {
            int k0 = 2 * c, k1 = k0 + 1;
            if (k0 < NODE_IN) v0 = f2bf_bits(nW[k0 * H + jj]);
            else if (k0 == 74) v0 = f2bf_bits(nb[jj]);
            else if (k0 == 75) { float b = nb[jj]; v0 = lo_bits(b, f2bf_bits(b)); }
            if (k1 < NODE_IN) v1 = f2bf_bits(nW[k1 * H + jj]);
            else if (k1 == 74) v1 = f2bf_bits(nb[jj]);
            else if (k1 == 75) { float b = nb[jj]; v1 = lo_bits(b, f2bf_bits(b)); }
        } else {
            int k0 = 2 * (c - 48), k1 = k0 + 1;
            if (k0 < NODE_IN) { float x = nW[k0 * H + jj]; v0 = lo_bits(x, f2bf_bits(x)); }
            if (k1 < NODE_IN) { float x = nW[k1 * H + jj]; v1 = lo_bits(x, f2bf_bits(x)); }
        }
    }
    BnW[idx] = v0 | (v1 << 16);
}

// ---------------- prep: pr_W -> transposed fp32 [2][H][H]: prWT[t][j][i] = pr_W[t][i][j] ----------------
__global__ __launch_bounds__(256) void k_prep_pw(const float* __restrict__ prW,
                                                 float* __restrict__ prWT) {
    int idx = blockIdx.x * 256 + threadIdx.x;
    if (idx >= 2 * H * H) return;
    int t = idx / (H * H);
    int rem = idx - t * H * H;
    int j = rem / H, i = rem - j * H;
    prWT[idx] = prW[t * H * H + i * H + j];
}

// ---------------- MEGA: embed + 5 GNN layers + gf; one block/graph; 3 blocks/CU ----------------
// agg layout per row (AGS=209 u32): chunk c in [0,26): k=8c..8c+7, hi8 bf16 @u16 c*16, lo8 @u16 c*16+8.
__global__ __launch_bounds__(256, 3) void k_mega(const unsigned short* __restrict__ Anf,
                                                 const unsigned short* __restrict__ BnW,
                                                 const unsigned short* __restrict__ Aedge,
                                                 const unsigned short* __restrict__ eWp,
                                                 const int* __restrict__ src,
                                                 const unsigned short* __restrict__ WtHi,
                                                 const unsigned short* __restrict__ WtLo,
                                                 const float* __restrict__ gnn_b,
                                                 float* __restrict__ h_out,
                                                 float* __restrict__ gf_out) {
    __shared__ alignas(16) float h_s[NPG * HS];           // 25600 B
    __shared__ alignas(16) unsigned int agg[NPG * AGS];   // 26752 B (also Anf staging)
    __shared__ alignas(16) unsigned int zpad[8];          // 32 B zeros (k>=208 A-source)
    __shared__ unsigned char src_s[NPG * DEG];            // 128 B  -> total 52512 B: 3 blocks/CU
    const int g = blockIdx.x, tid = threadIdx.x;
    const int nbase = g * NPG, ebase = g * NPG * DEG;

    const int wave = tid >> 6, lane = tid & 63;
    const int l15 = lane & 15, quad = lane >> 4;
    const int ntcnt = (wave == 0) ? 4 : 3;

    // edge A-fragments straight into registers (persist across all layers)
    short8 af[8];
    {
        const unsigned short* abase = Aedge + (size_t)ebase * EK;
#pragma unroll
        for (int mt = 0; mt < 8; mt++)
            af[mt] = *(const short8*)&abase[(16 * mt + l15) * EK + quad * 8];
    }
    if (tid < NPG * DEG) src_s[tid] = (unsigned char)(src[ebase + tid] - nbase);
    if (tid < 8) zpad[tid] = 0u;
    {
        const uint4* n4 = (const uint4*)(Anf + (size_t)nbase * NFS);
        uint4* d4 = (uint4*)agg;
        for (int p = tid; p < NPG * NFS * 2 / 16; p += 256) d4[p] = n4[p];
    }
    __syncthreads();

    // ---- embed: h = nf @ nW + nb (split-3 bf16 MFMA) ----
    {
        const unsigned short* nf_s = (const unsigned short*)agg;
        for (int i = 0; i < ntcnt; i++) {
            int nt = wave + 4 * i, jj = nt * 16 + l15;
            floatx4 acc[2];
            acc[0] = (floatx4){0.f, 0.f, 0.f, 0.f};
            acc[1] = (floatx4){0.f, 0.f, 0.f, 0.f};
            for (int ks = 0; ks < 3; ks++) {
                short8 bh = *(const short8*)&BnW[(size_t)jj * 192 + ks * 32 + quad * 8];
                short8 bl = *(const short8*)&BnW[(size_t)jj * 192 + 96 + ks * 32 + quad * 8];
#pragma unroll
                for (int mt = 0; mt < 2; mt++) {
                    const unsigned short* arow = nf_s + (16 * mt + l15) * NFS;
                    short8 ah = *(const short8*)&arow[ks * 32 + quad * 8];
                    short8 al = *(const short8*)&arow[96 + ks * 32 + quad * 8];
                    acc[mt] = __builtin_amdgcn_mfma_f32_16x16x32_bf16(ah, bh, acc[mt], 0, 0, 0);
                    acc[mt] = __builtin_amdgcn_mfma_f32_16x16x32_bf16(al, bh, acc[mt], 0, 0, 0);
                    acc[mt] = __builtin_amdgcn_mfma_f32_16x16x32_bf16(ah, bl, acc[mt], 0, 0, 0);
                }
            }
            if (jj < H) {
#pragma unroll
                for (int mt = 0; mt < 2; mt++)
#pragma unroll
                    for (int r = 0; r < 4; r++)
                        h_s[(16 * mt + quad * 4 + r) * HS + jj] = acc[mt][r];
            }
        }
    }
    __syncthreads();

    for (int l = 0; l < NL; l++) {
        // ---- phase 1: edge eh via MFMA + lane-local 4-edge softmax -> agg hi/lo chunks ----
        for (int i = 0; i < ntcnt; i++) {
            int nt = wave + 4 * i, jj = nt * 16 + l15;
            short8 b1 = *(const short8*)&eWp[(size_t)jj * 64 + quad * 8];
            short8 b2 = *(const short8*)&eWp[(size_t)jj * 64 + 32 + quad * 8];
            int jc = jj < H ? jj : H - 1;
#pragma unroll
            for (int mt = 0; mt < 8; mt++) {
                floatx4 z = (floatx4){0.f, 0.f, 0.f, 0.f};
                z = __builtin_amdgcn_mfma_f32_16x16x32_bf16(af[mt], b1, z, 0, 0, 0);
                z = __builtin_amdgcn_mfma_f32_16x16x32_bf16(af[mt], b2, z, 0, 0, 0);
                const int node = 4 * mt + quad;
                float m0 = z[0] + h_s[src_s[node * 4 + 0] * HS + jc];
                float m1 = z[1] + h_s[src_s[node * 4 + 1] * HS + jc];
                float m2 = z[2] + h_s[src_s[node * 4 + 2] * HS + jc];
                float m3 = z[3] + h_s[src_s[node * 4 + 3] * HS + jc];
                float mx = fmaxf(fmaxf(m0, m1), fmaxf(m2, m3));
                float e0 = __expf(m0 - mx), e1 = __expf(m1 - mx);
                float e2 = __expf(m2 - mx), e3 = __expf(m3 - mx);
                float den = e0 + e1 + e2 + e3;
                float num = fmaf(m0, e0, fmaf(m1, e1, fmaf(m2, e2, m3 * e3)));
                float a = __fdividef(num, den);
                if (jj >= H) a = 0.f;
                unsigned hbb = f2bf_bits(a);
                unsigned lbb = lo_bits(a, hbb);
                unsigned short* rowp = (unsigned short*)(agg + node * AGS);
                int c = jj >> 3, o = jj & 7;
                rowp[c * 16 + o] = (unsigned short)hbb;
                rowp[c * 16 + 8 + o] = (unsigned short)lbb;
            }
        }
        __syncthreads();

        // ---- phase 2: C[32][200] = agg @ W (split-3 MFMA), epilogue into h_s ----
        floatx4 acc2[2][4];
#pragma unroll
        for (int mt = 0; mt < 2; mt++)
#pragma unroll
            for (int i = 0; i < 4; i++) acc2[mt][i] = (floatx4){0.f, 0.f, 0.f, 0.f};

        const unsigned short* WH = WtHi + (size_t)l * NP * KP;
        const unsigned short* WL = WtLo + (size_t)l * NP * KP;
        for (int ks = 0; ks < KP / 32; ks++) {
            const int c = 4 * ks + quad;
            short8 ah[2], al[2];
#pragma unroll
            for (int mt = 0; mt < 2; mt++) {
                const unsigned int* ap = (c < 26) ? &agg[(16 * mt + l15) * AGS + c * 8]
                                                  : (const unsigned int*)zpad;
                ah[mt] = *(const short8*)ap;
                al[mt] = *(const short8*)(ap + 4);
            }
#pragma unroll 4
            for (int i = 0; i < ntcnt; i++) {
                int nt = wave + 4 * i;
                size_t boff = (size_t)(16 * nt + l15) * KP + ks * 32 + quad * 8;
                short8 vbh = *(const short8*)&WH[boff];
                short8 vbl = *(const short8*)&WL[boff];
#pragma unroll
                for (int mt = 0; mt < 2; mt++) {
                    acc2[mt][i] = __builtin_amdgcn_mfma_f32_16x16x32_bf16(ah[mt], vbh, acc2[mt][i], 0, 0, 0);
                    acc2[mt][i] = __builtin_amdgcn_mfma_f32_16x16x32_bf16(al[mt], vbh, acc2[mt][i], 0, 0, 0);
                    acc2[mt][i] = __builtin_amdgcn_mfma_f32_16x16x32_bf16(ah[mt], vbl, acc2[mt][i], 0, 0, 0);
                }
            }
        }
        for (int i = 0; i < ntcnt; i++) {
            int nt = wave + 4 * i, jj = nt * 16 + l15;
            if (jj < H) {
                float bj = gnn_b[l * H + jj];
#pragma unroll
                for (int mt = 0; mt < 2; mt++) {
#pragma unroll
                    for (int r = 0; r < 4; r++) {
                        float v = acc2[mt][i][r] + bj;
                        v = v > 0.f ? v : 0.f;
                        h_s[(16 * mt + quad * 4 + r) * HS + jj] += v;
                    }
                }
            }
        }
        __syncthreads();
    }

    // ---- write h + gf ----
    {
        float4* dst = (float4*)(h_out + (size_t)nbase * H);
        const float4* srcp = (const float4*)h_s;
        for (int p = tid; p < NPG * H / 4; p += 256) dst[p] = srcp[p];
    }
    if (tid < H) {
        float s = 0.f;
        for (int n = 0; n < NPG; n++) s += h_s[n * HS + tid];
        gf_out[g * H + tid] = s;
    }
}

// ---------------- readout attention: z/softmax/wh + ctx proj (transposed prW) ----------------
__global__ __launch_bounds__(256) void k_attn(const float* __restrict__ h,
                                              const float* __restrict__ gf,
                                              const float* __restrict__ lgW,
                                              const float* __restrict__ lgb,
                                              const float* __restrict__ prWT,  // [H][H], row j = col of pr_W
                                              const float* __restrict__ prb,
                                              float* __restrict__ ctx_out) {
    __shared__ float h_s[NPG][H];
    __shared__ float gf_s[H];
    __shared__ float zp[256];
    __shared__ float z_s[NPG];
    __shared__ float a_s[NPG];
    __shared__ alignas(16) float wh_s[H];
    const int g = blockIdx.x, tid = threadIdx.x;

    for (int p = tid; p < NPG * H; p += 256) h_s[0][p] = h[g * NPG * H + p];
    if (tid < H) gf_s[tid] = gf[g * H + tid];
    __syncthreads();

    // fused partials: zp[n*8+l] = sum_{jj=l mod 8} [ h[n][jj]*lgW[H+jj] + relu(gf[jj])*lgW[jj] ]
    {
        const int n = tid >> 3, l = tid & 7;
        float p = 0.f;
        for (int jj = l; jj < H; jj += 8) {
            p = fmaf(h_s[n][jj], lgW[H + jj], p);
            p = fmaf(fmaxf(gf_s[jj], 0.f), lgW[jj], p);
        }
        zp[tid] = p;
    }
    __syncthreads();
    if (tid < NPG) {
        float z = lgb[0];
        for (int q = 0; q < 8; q++) z += zp[tid * 8 + q];
        z_s[tid] = z > 0.f ? z : 0.01f * z;
    }
    __syncthreads();
    float zmax = -1e30f;
    for (int n = 0; n < NPG; n++) zmax = fmaxf(zmax, z_s[n]);
    if (tid < NPG) a_s[tid] = __expf(z_s[tid] - zmax);
    __syncthreads();
    float den = 0.f;
    for (int n = 0; n < NPG; n++) den += a_s[n];

    if (tid < H) {
        float s = 0.f;
        for (int n = 0; n < NPG; n++) s = fmaf(a_s[n], h_s[n][tid], s);
        wh_s[tid] = s / den;
    }
    __syncthreads();

    if (tid < H) {
        const float4* wr = (const float4*)(prWT + (size_t)tid * H);  // contiguous row
        float s0 = 0.f, s1 = 0.f, s2 = 0.f, s3 = 0.f;
        for (int i4 = 0; i4 < H / 4; i4 += 2) {
            float4 w0 = wr[i4], w1 = wr[i4 + 1];
            s0 = fmaf(wh_s[i4 * 4 + 0], w0.x, s0);
            s1 = fmaf(wh_s[i4 * 4 + 1], w0.y, s1);
            s2 = fmaf(wh_s[i4 * 4 + 2], w0.z, s2);
            s3 = fmaf(wh_s[i4 * 4 + 3], w0.w, s3);
            s0 = fmaf(wh_s[i4 * 4 + 4], w1.x, s0);
            s1 = fmaf(wh_s[i4 * 4 + 5], w1.y, s1);
            s2 = fmaf(wh_s[i4 * 4 + 6], w1.z, s2);
            s3 = fmaf(wh_s[i4 * 4 + 7], w1.w, s3);
        }
        float s = prb[tid] + ((s0 + s1) + (s2 + s3));
        ctx_out[g * H + tid] = s > 0.f ? s : __expf(s) - 1.f;  // elu
    }
}

// ---------------- GRU cell: float4 weight loads, 8 graphs per block ----------------
#define GPB 8
#define GP 9
__global__ __launch_bounds__(256) void k_gru(const float* __restrict__ ctx,
                                             const float* __restrict__ gf,
                                             const float* __restrict__ Wih,
                                             const float* __restrict__ Whh,
                                             const float* __restrict__ bih,
                                             const float* __restrict__ bhh,
                                             float* __restrict__ gf_out) {
    __shared__ float ctx_s[GPB][H];
    __shared__ float gfs[GPB][H];
    __shared__ float gi_s[3 * H][GP];
    __shared__ float gh_s[3 * H][GP];
    const int gbase = blockIdx.x * GPB, tid = threadIdx.x;

    for (int p = tid; p < GPB * H; p += 256) {
        ctx_s[0][p] = ctx[gbase * H + p];
        gfs[0][p] = gf[gbase * H + p];
    }
    __syncthreads();

    for (int k = tid; k < 3 * H; k += 256) {
        float ai[GPB], ah[GPB];
        float bi = bih[k], bh = bhh[k];
#pragma unroll
        for (int q = 0; q < GPB; q++) { ai[q] = bi; ah[q] = bh; }
        const float4* wi4 = (const float4*)(Wih + (size_t)k * H);  // rows 16B-aligned (k*800)
        const float4* wh4 = (const float4*)(Whh + (size_t)k * H);
        for (int j4 = 0; j4 < H / 4; j4++) {
            float4 wi = wi4[j4];
            float4 wh = wh4[j4];
            int jj = j4 * 4;
#pragma unroll
            for (int q = 0; q < GPB; q++) {
                ai[q] = fmaf(ctx_s[q][jj + 0], wi.x, ai[q]);
                ai[q] = fmaf(ctx_s[q][jj + 1], wi.y, ai[q]);
                ai[q] = fmaf(ctx_s[q][jj + 2], wi.z, ai[q]);
                ai[q] = fmaf(ctx_s[q][jj + 3], wi.w, ai[q]);
                ah[q] = fmaf(gfs[q][jj + 0], wh.x, ah[q]);
                ah[q] = fmaf(gfs[q][jj + 1], wh.y, ah[q]);
                ah[q] = fmaf(gfs[q][jj + 2], wh.z, ah[q]);
                ah[q] = fmaf(gfs[q][jj + 3], wh.w, ah[q]);
            }
        }
#pragma unroll
        for (int q = 0; q < GPB; q++) { gi_s[k][q] = ai[q]; gh_s[k][q] = ah[q]; }
    }
    __syncthreads();

    for (int p = tid; p < GPB * H; p += 256) {
        int q = p / H, jj = p - q * H;
        float r = sigmoidf_(gi_s[jj][q] + gh_s[jj][q]);
        float u = sigmoidf_(gi_s[H + jj][q] + gh_s[H + jj][q]);
        float nn = tanhf(gi_s[2 * H + jj][q] + r * gh_s[2 * H + jj][q]);
        gf_out[(gbase + q) * H + jj] = (1.f - u) * nn + u * gfs[q][jj];
    }
}

extern "C" void kernel_launch(void* const* d_in, const int* in_sizes, int n_in,
                              void* d_out, int out_size, void* d_ws, size_t ws_size,
                              hipStream_t stream) {
    const float* node_feat = (const float*)d_in[0];
    const float* edge_feat = (const float*)d_in[1];
    const int* src = (const int*)d_in[2];
    const float* node_W = (const float*)d_in[5];
    const float* node_b = (const float*)d_in[6];
    const float* edge_W = (const float*)d_in[7];
    const float* edge_b = (const float*)d_in[8];
    const float* gnn_W = (const float*)d_in[9];
    const float* gnn_b = (const float*)d_in[10];
    const float* lg_W = (const float*)d_in[11];
    const float* lg_b = (const float*)d_in[12];
    const float* pr_W = (const float*)d_in[13];
    const float* pr_b = (const float*)d_in[14];
    const float* W_ih = (const float*)d_in[15];
    const float* W_hh = (const float*)d_in[16];
    const float* b_ih = (const float*)d_in[17];
    const float* b_hh = (const float*)d_in[18];
    float* out = (float*)d_out;

    char* ws = (char*)d_ws;
    size_t off = 0;
    auto alloc = [&](size_t bytes) { void* p = ws + off; off += (bytes + 4095) & ~(size_t)4095; return p; };
    float* h = (float*)alloc((size_t)V * H * 4);
    unsigned short* Anf = (unsigned short*)alloc((size_t)V * NFS * 2);
    unsigned short* Aedge = (unsigned short*)alloc((size_t)NE * EK * 2);
    unsigned short* WtHi = (unsigned short*)alloc((size_t)NL * NP * KP * 2);
    unsigned short* WtLo = (unsigned short*)alloc((size_t)NL * NP * KP * 2);
    unsigned short* BnW = (unsigned short*)alloc((size_t)NP * 192 * 2);
    unsigned short* eWp = (unsigned short*)alloc((size_t)NP * 64 * 2);
    float* prWT = (float*)alloc((size_t)2 * H * H * 4);
    float* gf_ws = (float*)alloc((size_t)G * H * 4);
    float* ctx_ws = (float*)alloc((size_t)G * H * 4);

    k_prep_w<<<(NL * NP * KP + 255) / 256, 256, 0, stream>>>(gnn_W, WtHi, WtLo);
    k_prep_ew<<<1, 256, 0, stream>>>(edge_W, edge_b, eWp);
    k_prep_ef<<<NE / 256, 256, 0, stream>>>(edge_feat, Aedge);
    k_prep_nf<<<V / 64, 256, 0, stream>>>(node_feat, (unsigned int*)Anf);
    k_prep_nw<<<(NP * 96 + 255) / 256, 256, 0, stream>>>(node_W, node_b, (unsigned int*)BnW);
    k_prep_pw<<<(2 * H * H + 255) / 256, 256, 0, stream>>>(pr_W, prWT);

    k_mega<<<G, 256, 0, stream>>>(Anf, BnW, Aedge, eWp, src, WtHi, WtLo, gnn_b, h, gf_ws);

    for (int t = 0; t < 2; t++) {
        k_attn<<<G, 256, 0, stream>>>(h, gf_ws, lg_W + (size_t)t * 2 * H, lg_b + t,
                                      prWT + (size_t)t * H * H, pr_b + (size_t)t * H, ctx_ws);
        float* gout = (t == 1) ? out : gf_ws;
        k_gru<<<G / GPB, 256, 0, stream>>>(ctx_ws, gf_ws, W_ih + (size_t)t * 3 * H * H,
                                           W_hh + (size_t)t * 3 * H * H, b_ih + (size_t)t * 3 * H,
                                           b_hh + (size_t)t * 3 * H, gout);
    }
}

// Round 9
// 770.864 us; speedup vs baseline: 1.1541x; 1.0329x over previous
//
#include <hip/hip_runtime.h>
#include <hip/hip_bf16.h>
#include <math.h>

#define V 65536
#define G 2048
#define NPG 32
#define DEG 4
#define NE (V*DEG)
#define H 200
#define NODE_IN 74
#define EDGE_IN 12
#define NL 5

#define KP 224      // GEMM K padded (7 x 32)
#define NP 208      // feature dim padded (13 x 16)
#define AGS 209     // agg LDS row stride in u32 (209%32=17 -> spread banks on b128)
#define EK 32       // edge-mfma K
#define HS 200      // h_s row stride (floats) -- R7-proven

typedef __attribute__((ext_vector_type(8))) short short8;
typedef __attribute__((ext_vector_type(4))) float floatx4;

__device__ __forceinline__ float sigmoidf_(float x) { return 1.f / (1.f + __expf(-x)); }

__device__ __forceinline__ unsigned f2bf_bits(float f) {
    unsigned u = __float_as_uint(f);
    return (u + 0x7fffu + ((u >> 16) & 1u)) >> 16;  // RNE
}
__device__ __forceinline__ float bf2f(unsigned bits) { return __uint_as_float(bits << 16); }
__device__ __forceinline__ unsigned lo_bits(float f, unsigned hb) {
    return f2bf_bits(f - bf2f(hb));
}

// ---------------- node embedding (R1-proven, fp32): h = node_feat @ node_W + node_b ----------------
__global__ __launch_bounds__(256) void k_node_embed(const float* __restrict__ nf,
                                                    const float* __restrict__ W,
                                                    const float* __restrict__ b,
                                                    float* __restrict__ h) {
    __shared__ float fs[16][NODE_IN];
    const int tid = threadIdx.x;
    const int base = blockIdx.x * 16;
    for (int p = tid; p < 16 * NODE_IN; p += 256) {
        int n = p / NODE_IN, i = p - n * NODE_IN;
        fs[n][i] = nf[(base + n) * NODE_IN + i];
    }
    __syncthreads();
    const int j = tid;
    if (j < H) {
        float acc[16];
#pragma unroll
        for (int n = 0; n < 16; n++) acc[n] = 0.f;
        for (int i = 0; i < NODE_IN; i++) {
            float w = W[i * H + j];
#pragma unroll
            for (int n = 0; n < 16; n++) acc[n] = fmaf(fs[n][i], w, acc[n]);
        }
        float bj = b[j];
        for (int n = 0; n < 16; n++) h[(base + n) * H + j] = acc[n] + bj;
    }
}

// ---------------- merged small preps: gnn_W planes + edge_W planes + prWT ----------------
#define SEG_W (NL * NP * KP)          // 232960
#define SEG_EW NP                    // 208
#define SEG_PW (2 * H * H)           // 80000
__global__ __launch_bounds__(256) void k_prep_all(const float* __restrict__ gnnW,
                                                  const float* __restrict__ eW,
                                                  const float* __restrict__ eb,
                                                  const float* __restrict__ prW,
                                                  unsigned short* __restrict__ WtHi,
                                                  unsigned short* __restrict__ WtLo,
                                                  unsigned short* __restrict__ eWp,
                                                  float* __restrict__ prWT) {
    int idx = blockIdx.x * 256 + threadIdx.x;
    if (idx < SEG_W) {
        int l = idx / (NP * KP);
        int rem = idx - l * (NP * KP);
        int n = rem / KP;
        int k = rem - n * KP;
        float w = (n < H && k < H) ? gnnW[l * H * H + k * H + n] : 0.f;
        unsigned hb = f2bf_bits(w);
        WtHi[idx] = (unsigned short)hb;
        WtLo[idx] = (unsigned short)lo_bits(w, hb);
        return;
    }
    idx -= SEG_W;
    if (idx < SEG_EW) {
        int t = idx;
        unsigned short row[64];
        for (int i = 0; i < 64; i++) row[i] = 0;
        if (t < H) {
            for (int k = 0; k < EDGE_IN; k++) {
                float w = eW[k * H + t];
                unsigned hb = f2bf_bits(w);
                row[k] = (unsigned short)hb;
                row[12 + k] = (unsigned short)hb;
                row[32 + k] = (unsigned short)lo_bits(w, hb);
            }
            float e = eb[t];
            unsigned ebh = f2bf_bits(e);
            row[24] = (unsigned short)ebh;
            row[25] = (unsigned short)lo_bits(e, ebh);
        }
        for (int i = 0; i < 64; i++) eWp[t * 64 + i] = row[i];
        return;
    }
    idx -= SEG_EW;
    if (idx < SEG_PW) {
        int t = idx / (H * H);
        int rem = idx - t * (H * H);
        int j = rem / H, i = rem - j * H;
        prWT[idx] = prW[t * H * H + i * H + j];
    }
}

// ---------------- prep: ef -> edge A-plane [NE][EK]: [hi12 | lo12 | 1,1 | 0...] ----------------
__global__ __launch_bounds__(256) void k_prep_ef(const float* __restrict__ ef,
                                                 unsigned short* __restrict__ Aedge) {
    __shared__ float efs[256 * EDGE_IN];
    const int tid = threadIdx.x, blk = blockIdx.x;
    const float4* gs = (const float4*)(ef + (size_t)blk * 256 * EDGE_IN);
    float4* ds = (float4*)efs;
    for (int p = tid; p < 256 * EDGE_IN / 4; p += 256) ds[p] = gs[p];
    __syncthreads();
    unsigned hb[EDGE_IN], lb[EDGE_IN];
    for (int k = 0; k < EDGE_IN; k++) {
        float v = efs[tid * EDGE_IN + k];
        hb[k] = f2bf_bits(v);
        lb[k] = lo_bits(v, hb[k]);
    }
    unsigned w[16];
    for (int i = 0; i < 6; i++) w[i] = hb[2 * i] | (hb[2 * i + 1] << 16);
    for (int i = 0; i < 6; i++) w[6 + i] = lb[2 * i] | (lb[2 * i + 1] << 16);
    w[12] = 0x3F803F80u;  // k24,k25 = 1.0 (bias rows)
    w[13] = 0u; w[14] = 0u; w[15] = 0u;
    uint4* dst = (uint4*)(Aedge + ((size_t)blk * 256 + tid) * EK);
    dst[0] = make_uint4(w[0], w[1], w[2], w[3]);
    dst[1] = make_uint4(w[4], w[5], w[6], w[7]);
    dst[2] = make_uint4(w[8], w[9], w[10], w[11]);
    dst[3] = make_uint4(w[12], w[13], w[14], w[15]);
}

// ---------------- MEGA: 5 GNN layers + gf; one block/graph; 3 blocks/CU; split-3 (R7 numerics) ----
// agg layout per row (AGS=209 u32): chunk c in [0,26): k=8c..8c+7, hi8 bf16 @u16 c*16, lo8 @u16 c*16+8.
__global__ __launch_bounds__(256, 3) void k_mega(float* __restrict__ h,
                                                 const unsigned short* __restrict__ Aedge,
                                                 const unsigned short* __restrict__ eWp,
                                                 const int* __restrict__ src,
                                                 const unsigned short* __restrict__ WtHi,
                                                 const unsigned short* __restrict__ WtLo,
                                                 const float* __restrict__ gnn_b,
                                                 float* __restrict__ gf_out) {
    __shared__ alignas(16) float h_s[NPG * HS];           // 25600 B
    __shared__ alignas(16) unsigned int agg[NPG * AGS];   // 26752 B
    __shared__ alignas(16) unsigned int zpad[8];          // 32 B zeros (k>=208 A-source)
    __shared__ unsigned char src_s[NPG * DEG];            // 128 B  -> total 52512 B: 3 blocks/CU
    const int g = blockIdx.x, tid = threadIdx.x;
    const int nbase = g * NPG, ebase = g * NPG * DEG;

    const int wave = tid >> 6, lane = tid & 63;
    const int l15 = lane & 15, quad = lane >> 4;
    const int ntcnt = (wave == 0) ? 4 : 3;

    // edge A-fragments straight into registers (persist across all layers)
    short8 af[8];
    {
        const unsigned short* abase = Aedge + (size_t)ebase * EK;
#pragma unroll
        for (int mt = 0; mt < 8; mt++)
            af[mt] = *(const short8*)&abase[(16 * mt + l15) * EK + quad * 8];
    }
    if (tid < NPG * DEG) src_s[tid] = (unsigned char)(src[ebase + tid] - nbase);
    if (tid < 8) zpad[tid] = 0u;
    {
        const float4* hsrc = (const float4*)(h + (size_t)nbase * H);
        float4* hdst = (float4*)h_s;
        for (int p = tid; p < NPG * H / 4; p += 256) hdst[p] = hsrc[p];
    }
    __syncthreads();

    for (int l = 0; l < NL; l++) {
        // ---- phase 1: hoisted gathers + edge eh via MFMA + lane-local softmax -> agg hi/lo ----
        for (int i = 0; i < ntcnt; i++) {
            int nt = wave + 4 * i, jj = nt * 16 + l15;
            short8 b1 = *(const short8*)&eWp[(size_t)jj * 64 + quad * 8];
            short8 b2 = *(const short8*)&eWp[(size_t)jj * 64 + 32 + quad * 8];
            int jc = jj < H ? jj : H - 1;
            // hoist all 32 h-gathers for this i before the MFMA/softmax chain
            float mh[8][4];
#pragma unroll
            for (int mt = 0; mt < 8; mt++) {
                const int node = 4 * mt + quad;
#pragma unroll
                for (int e = 0; e < 4; e++)
                    mh[mt][e] = h_s[src_s[node * 4 + e] * HS + jc];
            }
#pragma unroll
            for (int mt = 0; mt < 8; mt++) {
                floatx4 z = (floatx4){0.f, 0.f, 0.f, 0.f};
                z = __builtin_amdgcn_mfma_f32_16x16x32_bf16(af[mt], b1, z, 0, 0, 0);
                z = __builtin_amdgcn_mfma_f32_16x16x32_bf16(af[mt], b2, z, 0, 0, 0);
                const int node = 4 * mt + quad;
                float m0 = z[0] + mh[mt][0];
                float m1 = z[1] + mh[mt][1];
                float m2 = z[2] + mh[mt][2];
                float m3 = z[3] + mh[mt][3];
                float mx = fmaxf(fmaxf(m0, m1), fmaxf(m2, m3));
                float e0 = __expf(m0 - mx), e1 = __expf(m1 - mx);
                float e2 = __expf(m2 - mx), e3 = __expf(m3 - mx);
                float den = e0 + e1 + e2 + e3;
                float num = fmaf(m0, e0, fmaf(m1, e1, fmaf(m2, e2, m3 * e3)));
                float a = __fdividef(num, den);
                if (jj >= H) a = 0.f;
                unsigned hbb = f2bf_bits(a);
                unsigned lbb = lo_bits(a, hbb);
                unsigned short* rowp = (unsigned short*)(agg + node * AGS);
                int c = jj >> 3, o = jj & 7;
                rowp[c * 16 + o] = (unsigned short)hbb;
                rowp[c * 16 + 8 + o] = (unsigned short)lbb;
            }
        }
        __syncthreads();

        // ---- phase 2: C[32][200] = agg @ W (split-3 MFMA), epilogue into h_s ----
        floatx4 acc2[2][4];
#pragma unroll
        for (int mt = 0; mt < 2; mt++)
#pragma unroll
            for (int i = 0; i < 4; i++) acc2[mt][i] = (floatx4){0.f, 0.f, 0.f, 0.f};

        const unsigned short* WH = WtHi + (size_t)l * NP * KP;
        const unsigned short* WL = WtLo + (size_t)l * NP * KP;
        for (int ks = 0; ks < KP / 32; ks++) {
            const int c = 4 * ks + quad;
            short8 ah[2], al[2];
#pragma unroll
            for (int mt = 0; mt < 2; mt++) {
                const unsigned int* ap = (c < 26) ? &agg[(16 * mt + l15) * AGS + c * 8]
                                                  : (const unsigned int*)zpad;
                ah[mt] = *(const short8*)ap;
                al[mt] = *(const short8*)(ap + 4);
            }
#pragma unroll 4
            for (int i = 0; i < ntcnt; i++) {
                int nt = wave + 4 * i;
                size_t boff = (size_t)(16 * nt + l15) * KP + ks * 32 + quad * 8;
                short8 vbh = *(const short8*)&WH[boff];
                short8 vbl = *(const short8*)&WL[boff];
#pragma unroll
                for (int mt = 0; mt < 2; mt++) {
                    acc2[mt][i] = __builtin_amdgcn_mfma_f32_16x16x32_bf16(ah[mt], vbh, acc2[mt][i], 0, 0, 0);
                    acc2[mt][i] = __builtin_amdgcn_mfma_f32_16x16x32_bf16(al[mt], vbh, acc2[mt][i], 0, 0, 0);
                    acc2[mt][i] = __builtin_amdgcn_mfma_f32_16x16x32_bf16(ah[mt], vbl, acc2[mt][i], 0, 0, 0);
                }
            }
        }
        for (int i = 0; i < ntcnt; i++) {
            int nt = wave + 4 * i, jj = nt * 16 + l15;
            if (jj < H) {
                float bj = gnn_b[l * H + jj];
#pragma unroll
                for (int mt = 0; mt < 2; mt++) {
#pragma unroll
                    for (int r = 0; r < 4; r++) {
                        float v = acc2[mt][i][r] + bj;
                        v = v > 0.f ? v : 0.f;
                        h_s[(16 * mt + quad * 4 + r) * HS + jj] += v;
                    }
                }
            }
        }
        __syncthreads();
    }

    // ---- write h + gf ----
    {
        float4* dst = (float4*)(h + (size_t)nbase * H);
        const float4* srcp = (const float4*)h_s;
        for (int p = tid; p < NPG * H / 4; p += 256) dst[p] = srcp[p];
    }
    if (tid < H) {
        float s = 0.f;
        for (int n = 0; n < NPG; n++) s += h_s[n * HS + tid];
        gf_out[g * H + tid] = s;
    }
}

// ---------------- readout attention (R7 version, passing) ----------------
__global__ __launch_bounds__(256) void k_attn(const float* __restrict__ h,
                                              const float* __restrict__ gf,
                                              const float* __restrict__ lgW,
                                              const float* __restrict__ lgb,
                                              const float* __restrict__ prWT,
                                              const float* __restrict__ prb,
                                              float* __restrict__ ctx_out) {
    __shared__ float h_s[NPG][H];
    __shared__ float gf_s[H];
    __shared__ float zp[256];
    __shared__ float z_s[NPG];
    __shared__ float a_s[NPG];
    __shared__ alignas(16) float wh_s[H];
    const int g = blockIdx.x, tid = threadIdx.x;

    for (int p = tid; p < NPG * H; p += 256) h_s[0][p] = h[g * NPG * H + p];
    if (tid < H) gf_s[tid] = gf[g * H + tid];
    __syncthreads();

    {
        const int n = tid >> 3, l = tid & 7;
        float p = 0.f;
        for (int jj = l; jj < H; jj += 8) {
            p = fmaf(h_s[n][jj], lgW[H + jj], p);
            p = fmaf(fmaxf(gf_s[jj], 0.f), lgW[jj], p);
        }
        zp[tid] = p;
    }
    __syncthreads();
    if (tid < NPG) {
        float z = lgb[0];
        for (int q = 0; q < 8; q++) z += zp[tid * 8 + q];
        z_s[tid] = z > 0.f ? z : 0.01f * z;
    }
    __syncthreads();
    float zmax = -1e30f;
    for (int n = 0; n < NPG; n++) zmax = fmaxf(zmax, z_s[n]);
    if (tid < NPG) a_s[tid] = __expf(z_s[tid] - zmax);
    __syncthreads();
    float den = 0.f;
    for (int n = 0; n < NPG; n++) den += a_s[n];

    if (tid < H) {
        float s = 0.f;
        for (int n = 0; n < NPG; n++) s = fmaf(a_s[n], h_s[n][tid], s);
        wh_s[tid] = s / den;
    }
    __syncthreads();

    if (tid < H) {
        const float4* wr = (const float4*)(prWT + (size_t)tid * H);
        float s0 = 0.f, s1 = 0.f, s2 = 0.f, s3 = 0.f;
        for (int i4 = 0; i4 < H / 4; i4 += 2) {
            float4 w0 = wr[i4], w1 = wr[i4 + 1];
            s0 = fmaf(wh_s[i4 * 4 + 0], w0.x, s0);
            s1 = fmaf(wh_s[i4 * 4 + 1], w0.y, s1);
            s2 = fmaf(wh_s[i4 * 4 + 2], w0.z, s2);
            s3 = fmaf(wh_s[i4 * 4 + 3], w0.w, s3);
            s0 = fmaf(wh_s[i4 * 4 + 4], w1.x, s0);
            s1 = fmaf(wh_s[i4 * 4 + 5], w1.y, s1);
            s2 = fmaf(wh_s[i4 * 4 + 6], w1.z, s2);
            s3 = fmaf(wh_s[i4 * 4 + 7], w1.w, s3);
        }
        float s = prb[tid] + ((s0 + s1) + (s2 + s3));
        ctx_out[g * H + tid] = s > 0.f ? s : __expf(s) - 1.f;
    }
}

// ---------------- GRU cell (R7 version, passing) ----------------
#define GPB 8
#define GP 9
__global__ __launch_bounds__(256) void k_gru(const float* __restrict__ ctx,
                                             const float* __restrict__ gf,
                                             const float* __restrict__ Wih,
                                             const float* __restrict__ Whh,
                                             const float* __restrict__ bih,
                                             const float* __restrict__ bhh,
                                             float* __restrict__ gf_out) {
    __shared__ float ctx_s[GPB][H];
    __shared__ float gfs[GPB][H];
    __shared__ float gi_s[3 * H][GP];
    __shared__ float gh_s[3 * H][GP];
    const int gbase = blockIdx.x * GPB, tid = threadIdx.x;

    for (int p = tid; p < GPB * H; p += 256) {
        ctx_s[0][p] = ctx[gbase * H + p];
        gfs[0][p] = gf[gbase * H + p];
    }
    __syncthreads();

    for (int k = tid; k < 3 * H; k += 256) {
        float ai[GPB], ah[GPB];
        float bi = bih[k], bh = bhh[k];
#pragma unroll
        for (int q = 0; q < GPB; q++) { ai[q] = bi; ah[q] = bh; }
        const float4* wi4 = (const float4*)(Wih + (size_t)k * H);
        const float4* wh4 = (const float4*)(Whh + (size_t)k * H);
        for (int j4 = 0; j4 < H / 4; j4++) {
            float4 wi = wi4[j4];
            float4 wh = wh4[j4];
            int jj = j4 * 4;
#pragma unroll
            for (int q = 0; q < GPB; q++) {
                ai[q] = fmaf(ctx_s[q][jj + 0], wi.x, ai[q]);
                ai[q] = fmaf(ctx_s[q][jj + 1], wi.y, ai[q]);
                ai[q] = fmaf(ctx_s[q][jj + 2], wi.z, ai[q]);
                ai[q] = fmaf(ctx_s[q][jj + 3], wi.w, ai[q]);
                ah[q] = fmaf(gfs[q][jj + 0], wh.x, ah[q]);
                ah[q] = fmaf(gfs[q][jj + 1], wh.y, ah[q]);
                ah[q] = fmaf(gfs[q][jj + 2], wh.z, ah[q]);
                ah[q] = fmaf(gfs[q][jj + 3], wh.w, ah[q]);
            }
        }
#pragma unroll
        for (int q = 0; q < GPB; q++) { gi_s[k][q] = ai[q]; gh_s[k][q] = ah[q]; }
    }
    __syncthreads();

    for (int p = tid; p < GPB * H; p += 256) {
        int q = p / H, jj = p - q * H;
        float r = sigmoidf_(gi_s[jj][q] + gh_s[jj][q]);
        float u = sigmoidf_(gi_s[H + jj][q] + gh_s[H + jj][q]);
        float nn = tanhf(gi_s[2 * H + jj][q] + r * gh_s[2 * H + jj][q]);
        gf_out[(gbase + q) * H + jj] = (1.f - u) * nn + u * gfs[q][jj];
    }
}

extern "C" void kernel_launch(void* const* d_in, const int* in_sizes, int n_in,
                              void* d_out, int out_size, void* d_ws, size_t ws_size,
                              hipStream_t stream) {
    const float* node_feat = (const float*)d_in[0];
    const float* edge_feat = (const float*)d_in[1];
    const int* src = (const int*)d_in[2];
    const float* node_W = (const float*)d_in[5];
    const float* node_b = (const float*)d_in[6];
    const float* edge_W = (const float*)d_in[7];
    const float* edge_b = (const float*)d_in[8];
    const float* gnn_W = (const float*)d_in[9];
    const float* gnn_b = (const float*)d_in[10];
    const float* lg_W = (const float*)d_in[11];
    const float* lg_b = (const float*)d_in[12];
    const float* pr_W = (const float*)d_in[13];
    const float* pr_b = (const float*)d_in[14];
    const float* W_ih = (const float*)d_in[15];
    const float* W_hh = (const float*)d_in[16];
    const float* b_ih = (const float*)d_in[17];
    const float* b_hh = (const float*)d_in[18];
    float* out = (float*)d_out;

    char* ws = (char*)d_ws;
    size_t off = 0;
    auto alloc = [&](size_t bytes) { void* p = ws + off; off += (bytes + 4095) & ~(size_t)4095; return p; };
    float* h = (float*)alloc((size_t)V * H * 4);
    unsigned short* Aedge = (unsigned short*)alloc((size_t)NE * EK * 2);
    unsigned short* WtHi = (unsigned short*)alloc((size_t)NL * NP * KP * 2);
    unsigned short* WtLo = (unsigned short*)alloc((size_t)NL * NP * KP * 2);
    unsigned short* eWp = (unsigned short*)alloc((size_t)NP * 64 * 2);
    float* prWT = (float*)alloc((size_t)2 * H * H * 4);
    float* gf_ws = (float*)alloc((size_t)G * H * 4);
    float* ctx_ws = (float*)alloc((size_t)G * H * 4);

    {
        int total = SEG_W + SEG_EW + SEG_PW;
        k_prep_all<<<(total + 255) / 256, 256, 0, stream>>>(gnn_W, edge_W, edge_b, pr_W,
                                                            WtHi, WtLo, eWp, prWT);
    }
    k_prep_ef<<<NE / 256, 256, 0, stream>>>(edge_feat, Aedge);
    k_node_embed<<<V / 16, 256, 0, stream>>>(node_feat, node_W, node_b, h);

    k_mega<<<G, 256, 0, stream>>>(h, Aedge, eWp, src, WtHi, WtLo, gnn_b, gf_ws);

    for (int t = 0; t < 2; t++) {
        k_attn<<<G, 256, 0, stream>>>(h, gf_ws, lg_W + (size_t)t * 2 * H, lg_b + t,
                                      prWT + (size_t)t * H * H, pr_b + (size_t)t * H, ctx_ws);
        float* gout = (t == 1) ? out : gf_ws;
        k_gru<<<G / GPB, 256, 0, stream>>>(ctx_ws, gf_ws, W_ih + (size_t)t * 3 * H * H,
                                           W_hh + (size_t)t * 3 * H * H, b_ih + (size_t)t * 3 * H,
                                           b_hh + (size_t)t * 3 * H, gout);
    }
}